// Round 1
// baseline (8337.545 us; speedup 1.0000x reference)
//
#include <hip/hip_runtime.h>

typedef unsigned short ushort_t;
typedef __attribute__((ext_vector_type(8))) short short8;
typedef __attribute__((ext_vector_type(4))) float floatx4;

// ---------------- constants ----------------
#define B_  128
#define T_  32
#define S_  512
#define H_  1024
#define IN_ 1024

// output offsets (f32 elements)
#define O0 0            // output_ [B,T,H]
#define O1 4194304      // h [B,H]
#define O2 4325376      // c [B,H]
#define O3 4456448      // h_attn_out [B,H]
#define O4 4587520      // out_attn [T,B,S]
#define O5 6684672      // past_attn [B,S]
#define O6 6750208      // p_gen [B,T]
#define O7 6754304      // past_dehy [B,1,H]
#define O8 6885376      // loss_cv [1]

__device__ __forceinline__ unsigned short f2bf(float f) {
  unsigned u = __float_as_uint(f);
  u += 0x7fffu + ((u >> 16) & 1u);
  return (unsigned short)(u >> 16);
}
__device__ __forceinline__ float bf2f(unsigned short s) {
  return __uint_as_float(((unsigned)s) << 16);
}
__device__ __forceinline__ float sigmoidf_(float x) { return 1.f / (1.f + __expf(-x)); }

// ---------------- converts ----------------
__global__ void k_conv_direct(const float* __restrict__ src, unsigned short* __restrict__ dst, int n) {
  int i = blockIdx.x * 256 + threadIdx.x;
  if (i < n) dst[i] = f2bf(src[i]);
}
// Wc[n][k]: k<1024 -> W_ih[n][IN+k] (ha part); k>=1024 -> W_hh[n][k-1024]
__global__ void k_conv_Wc(const float* __restrict__ W_ih, const float* __restrict__ W_hh,
                          unsigned short* __restrict__ Wc) {
  int i = blockIdx.x * 256 + threadIdx.x;  // 4096*2048
  int n = i >> 11, k = i & 2047;
  float v = (k < 1024) ? W_ih[(size_t)n * 2048 + 1024 + k] : W_hh[(size_t)n * 1024 + (k - 1024)];
  Wc[i] = f2bf(v);
}
// Wx[n][k] = W_ih[n][k], k<1024
__global__ void k_conv_Wx(const float* __restrict__ W_ih, unsigned short* __restrict__ Wx) {
  int i = blockIdx.x * 256 + threadIdx.x;  // 4096*1024
  int n = i >> 10, k = i & 1023;
  Wx[i] = f2bf(W_ih[(size_t)n * 2048 + k]);
}
// WaT[n][k] = W_attn[k][n]  (so htilde = h @ W_attn with B^T layout)
__global__ void k_conv_WaT(const float* __restrict__ W_attn, unsigned short* __restrict__ WaT) {
  int i = blockIdx.x * 256 + threadIdx.x;  // 1024*1024
  int n = i >> 10, k = i & 1023;
  WaT[i] = f2bf(W_attn[(size_t)k * 1024 + n]);
}

// ---------------- init ----------------
__global__ void k_init(const float* __restrict__ hidden_h, const float* __restrict__ hidden_c,
                       const float* __restrict__ h_attn, const float* __restrict__ past_attn,
                       const float* __restrict__ past_dehy, const float* __restrict__ b_ih,
                       const float* __restrict__ b_hh, unsigned short* __restrict__ A,
                       float* __restrict__ hbuf, float* __restrict__ cbuf,
                       float* __restrict__ bc, float* __restrict__ out) {
  int i = blockIdx.x * 256 + threadIdx.x;  // 131072 threads
  if (i < B_ * H_) {
    int b = i >> 10, j = i & 1023;
    A[(size_t)b * 2048 + j] = f2bf(h_attn[i]);
    A[(size_t)b * 2048 + 1024 + j] = f2bf(hidden_h[i]);
    hbuf[i] = hidden_h[i];
    cbuf[i] = hidden_c[i];
    out[O7 + i] = past_dehy[i];
  }
  if (i < B_ * S_) out[O5 + i] = past_attn[i];
  if (i < 4096) bc[i] = b_ih[i] + b_hh[i];
  if (i == 0) out[O8] = 0.f;
}

// ---------------- px precompute: px[m] = input_[m,:]·W_pt[0:1024] + b_pt ----------------
__global__ __launch_bounds__(64) void k_px(const float* __restrict__ input_,
                                           const float* __restrict__ W_pt,
                                           const float* __restrict__ b_pt,
                                           float* __restrict__ px) {
  int m = blockIdx.x;
  int lane = threadIdx.x;
  const float* x = input_ + (size_t)m * 1024;
  float s = 0.f;
  for (int j = lane; j < 1024; j += 64) s += x[j] * W_pt[j];
  for (int off = 32; off; off >>= 1) s += __shfl_down(s, off);
  if (lane == 0) px[m] = s + b_pt[0];
}

// ---------------- generic bf16 MFMA GEMM: C[M,N] = A[M,K] * B[N,K]^T (+bias +add) ----------------
__global__ __launch_bounds__(256) void k_gemm(
    const unsigned short* __restrict__ A, int lda,
    const unsigned short* __restrict__ B, int ldb, int K,
    const float* __restrict__ bias,
    const unsigned short* __restrict__ addb, long long addld,
    float* __restrict__ outf, long long outfld,
    unsigned short* __restrict__ outb, long long outbld) {
  __shared__ alignas(16) unsigned short As[64][72];
  __shared__ alignas(16) unsigned short Bs[64][72];
  const int m0 = blockIdx.x * 64, n0 = blockIdx.y * 64;
  const int t = threadIdx.x;
  const int lane = t & 63, wid = t >> 6;
  const int wm = wid >> 1, wn = wid & 1;
  const int sr = t >> 2, sk = (t & 3) << 4;
  const int l15 = lane & 15, lhi = lane >> 4;
  floatx4 acc[2][2];
#pragma unroll
  for (int i = 0; i < 2; i++)
#pragma unroll
    for (int j = 0; j < 2; j++) acc[i][j] = (floatx4){0.f, 0.f, 0.f, 0.f};

  for (int k0 = 0; k0 < K; k0 += 64) {
    const unsigned short* ga = A + (size_t)(m0 + sr) * lda + (k0 + sk);
    const unsigned short* gb = B + (size_t)(n0 + sr) * ldb + (k0 + sk);
    *(short8*)&As[sr][sk] = *(const short8*)ga;
    *(short8*)&As[sr][sk + 8] = *(const short8*)(ga + 8);
    *(short8*)&Bs[sr][sk] = *(const short8*)gb;
    *(short8*)&Bs[sr][sk + 8] = *(const short8*)(gb + 8);
    __syncthreads();
#pragma unroll
    for (int kk = 0; kk < 64; kk += 32) {
      const int kb = kk + lhi * 8;
      short8 af0 = *(const short8*)&As[wm * 32 + l15][kb];
      short8 af1 = *(const short8*)&As[wm * 32 + 16 + l15][kb];
      short8 bf0 = *(const short8*)&Bs[wn * 32 + l15][kb];
      short8 bf1 = *(const short8*)&Bs[wn * 32 + 16 + l15][kb];
      acc[0][0] = __builtin_amdgcn_mfma_f32_16x16x32_bf16(af0, bf0, acc[0][0], 0, 0, 0);
      acc[0][1] = __builtin_amdgcn_mfma_f32_16x16x32_bf16(af0, bf1, acc[0][1], 0, 0, 0);
      acc[1][0] = __builtin_amdgcn_mfma_f32_16x16x32_bf16(af1, bf0, acc[1][0], 0, 0, 0);
      acc[1][1] = __builtin_amdgcn_mfma_f32_16x16x32_bf16(af1, bf1, acc[1][1], 0, 0, 0);
    }
    __syncthreads();
  }
#pragma unroll
  for (int i = 0; i < 2; i++) {
    const int mb = m0 + wm * 32 + i * 16 + (lhi << 2);
#pragma unroll
    for (int j = 0; j < 2; j++) {
      const int n = n0 + wn * 32 + j * 16 + l15;
      const float bs = bias ? bias[n] : 0.f;
#pragma unroll
      for (int r = 0; r < 4; r++) {
        const int m = mb + r;
        float v = acc[i][j][r] + bs;
        if (addb) v += bf2f(addb[(size_t)m * addld + n]);
        if (outf) outf[(size_t)m * outfld + n] = v;
        if (outb) outb[(size_t)m * outbld + n] = f2bf(v);
      }
    }
  }
}

// ---------------- LSTM elementwise ----------------
__global__ void k_lstm(const float* __restrict__ gates, float* __restrict__ hbuf,
                       float* __restrict__ cbuf, unsigned short* __restrict__ A,
                       unsigned short* __restrict__ A2) {
  int i = blockIdx.x * 256 + threadIdx.x;  // B*H
  int b = i >> 10, j = i & 1023;
  const float* g = gates + (size_t)b * 4096;
  float iv = sigmoidf_(g[j]);
  float fv = sigmoidf_(g[1024 + j]);
  float gv = tanhf(g[2048 + j]);
  float ov = sigmoidf_(g[3072 + j]);
  float cn = fv * cbuf[i] + iv * gv;
  float hn = ov * tanhf(cn);
  cbuf[i] = cn;
  hbuf[i] = hn;
  unsigned short hb = f2bf(hn);
  A[(size_t)b * 2048 + 1024 + j] = hb;
  A2[(size_t)b * 2048 + 1024 + j] = hb;
}

// ---------------- attention: logits -> softmax -> weighted sum ----------------
__global__ __launch_bounds__(512) void k_attn(const float* __restrict__ enc,
                                              const float* __restrict__ htl,
                                              float* __restrict__ attn_out,
                                              float* __restrict__ cenc,
                                              unsigned short* __restrict__ A2) {
  const int b = blockIdx.x;
  const int t = threadIdx.x;
  const int lane = t & 63, wid = t >> 6;  // 8 waves
  __shared__ float logit[512];
  __shared__ float red[16];
  const float* encb = enc + (size_t)b * S_ * H_;
  // htilde into regs: 16 f32/lane
  floatx4 ht[4];
#pragma unroll
  for (int q = 0; q < 4; q++) ht[q] = *(const floatx4*)&htl[(size_t)b * 1024 + q * 256 + lane * 4];
  // phase 1: logits (wave per s)
  for (int s = wid; s < S_; s += 8) {
    const float* row = encb + (size_t)s * H_;
    float sum = 0.f;
#pragma unroll
    for (int q = 0; q < 4; q++) {
      floatx4 e = *(const floatx4*)&row[q * 256 + lane * 4];
      sum += e.x * ht[q].x + e.y * ht[q].y + e.z * ht[q].z + e.w * ht[q].w;
    }
    for (int off = 32; off; off >>= 1) sum += __shfl_down(sum, off);
    if (lane == 0) logit[s] = sum;
  }
  __syncthreads();
  // phase 2: softmax over 512
  float x = logit[t];
  float mx = x;
  for (int off = 32; off; off >>= 1) mx = fmaxf(mx, __shfl_xor(mx, off));
  if (lane == 0) red[wid] = mx;
  __syncthreads();
  float M = red[0];
#pragma unroll
  for (int w = 1; w < 8; w++) M = fmaxf(M, red[w]);
  float e = __expf(x - M);
  float sm = e;
  for (int off = 32; off; off >>= 1) sm += __shfl_xor(sm, off);
  __syncthreads();
  if (lane == 0) red[8 + wid] = sm;
  __syncthreads();
  float L = 0.f;
#pragma unroll
  for (int w = 0; w < 8; w++) L += red[8 + w];
  float at = e / L;
  logit[t] = at;
  attn_out[(size_t)b * S_ + t] = at;
  __syncthreads();
  // phase 3: c_enc[h] = sum_s attn[s]*enc[b,s,h]; threads cover h = t and t+512
  float a0 = 0.f, a1 = 0.f;
#pragma unroll 4
  for (int s = 0; s < S_; s++) {
    float w = logit[s];
    const float* row = encb + (size_t)s * H_;
    a0 += w * row[t];
    a1 += w * row[t + 512];
  }
  cenc[(size_t)b * 1024 + t] = a0;
  cenc[(size_t)b * 1024 + t + 512] = a1;
  A2[(size_t)b * 2048 + t] = f2bf(a0);
  A2[(size_t)b * 2048 + t + 512] = f2bf(a1);
}

// ---------------- p_gen ----------------
__global__ __launch_bounds__(64) void k_p(const float* __restrict__ hbuf,
                                          const float* __restrict__ cenc,
                                          const float* __restrict__ px,
                                          const float* __restrict__ W_pt,
                                          float* __restrict__ out, int k) {
  int b = blockIdx.x;
  int lane = threadIdx.x;
  const float* wh = W_pt + 1024;
  const float* wc = W_pt + 2048;
  float s = 0.f;
  for (int j = lane; j < 1024; j += 64)
    s += hbuf[(size_t)b * 1024 + j] * wh[j] + cenc[(size_t)b * 1024 + j] * wc[j];
  for (int off = 32; off; off >>= 1) s += __shfl_down(s, off);
  if (lane == 0) out[O6 + b * T_ + k] = sigmoidf_(s + px[b * T_ + k]);
}

// ---------------- finalize ----------------
__global__ void k_final(const float* __restrict__ hbuf, const float* __restrict__ cbuf,
                        float* __restrict__ out) {
  int i = blockIdx.x * 256 + threadIdx.x;  // B*H
  out[O1 + i] = hbuf[i];
  out[O2 + i] = cbuf[i];
  int b = i >> 10, j = i & 1023;
  out[O3 + i] = out[O0 + (size_t)b * (T_ * H_) + 31 * H_ + j];
}

// ---------------- host ----------------
extern "C" void kernel_launch(void* const* d_in, const int* in_sizes, int n_in,
                              void* d_out, int out_size, void* d_ws, size_t ws_size,
                              hipStream_t stream) {
  const float* input_ = (const float*)d_in[1];
  const float* hidden_h = (const float*)d_in[2];
  const float* hidden_c = (const float*)d_in[3];
  const float* h_attn = (const float*)d_in[4];
  const float* enc = (const float*)d_in[5];
  const float* past_attn = (const float*)d_in[6];
  const float* past_dehy = (const float*)d_in[8];
  const float* W_ih = (const float*)d_in[9];
  const float* b_ih = (const float*)d_in[10];
  const float* W_hh = (const float*)d_in[11];
  const float* b_hh = (const float*)d_in[12];
  const float* W_attn = (const float*)d_in[13];
  const float* W_out = (const float*)d_in[14];
  const float* b_out = (const float*)d_in[15];
  const float* W_pt = (const float*)d_in[16];
  const float* b_pt = (const float*)d_in[17];
  float* out = (float*)d_out;
  char* ws = (char*)d_ws;

  // workspace layout (bytes)
  unsigned short* Wc = (unsigned short*)(ws + 0);            // [4096][2048] bf16
  unsigned short* Wx = (unsigned short*)(ws + 16777216);     // [4096][1024]
  unsigned short* WaT = (unsigned short*)(ws + 25165824);    // [1024][1024]
  unsigned short* Wo = (unsigned short*)(ws + 27262976);     // [1024][2048]
  unsigned short* Xb = (unsigned short*)(ws + 31457280);     // [4096][1024]
  unsigned short* gx = (unsigned short*)(ws + 39845888);     // [4096][4096]
  float* bc = (float*)(ws + 73400320);                       // [4096]
  float* px = (float*)(ws + 73416704);                       // [4096]
  unsigned short* A = (unsigned short*)(ws + 73433088);      // [128][2048] = [ha|h]
  unsigned short* A2 = (unsigned short*)(ws + 73957376);     // [128][2048] = [c_enc|h]
  float* gates = (float*)(ws + 74481664);                    // [128][4096]
  float* hbuf = (float*)(ws + 76578816);                     // [128][1024]
  float* cbuf = (float*)(ws + 77103104);
  float* htl = (float*)(ws + 77627392);
  float* cenc = (float*)(ws + 78151680);

  // ---- precompute ----
  k_conv_Wc<<<4096 * 2048 / 256, 256, 0, stream>>>(W_ih, W_hh, Wc);
  k_conv_Wx<<<4096 * 1024 / 256, 256, 0, stream>>>(W_ih, Wx);
  k_conv_WaT<<<1024 * 1024 / 256, 256, 0, stream>>>(W_attn, WaT);
  k_conv_direct<<<1024 * 2048 / 256, 256, 0, stream>>>(W_out, Wo, 1024 * 2048);
  k_conv_direct<<<4096 * 1024 / 256, 256, 0, stream>>>(input_, Xb, 4096 * 1024);
  k_init<<<131072 / 256, 256, 0, stream>>>(hidden_h, hidden_c, h_attn, past_attn, past_dehy,
                                           b_ih, b_hh, A, hbuf, cbuf, bc, out);
  k_px<<<4096, 64, 0, stream>>>(input_, W_pt, b_pt, px);
  // gx[m][n] = Xb[m,:]·Wx[n,:] + bc[n]   (m = b*T + t)
  k_gemm<<<dim3(4096 / 64, 4096 / 64), 256, 0, stream>>>(
      Xb, 1024, Wx, 1024, 1024, bc, nullptr, 0, nullptr, 0, gx, 4096);

  // ---- recurrent loop ----
  for (int k = 0; k < T_; k++) {
    // gates = A([ha|h]) @ Wc^T + gx[:,k,:]
    k_gemm<<<dim3(2, 64), 256, 0, stream>>>(A, 2048, Wc, 2048, 2048, nullptr,
                                            gx + (size_t)k * 4096, (long long)T_ * 4096,
                                            gates, 4096, nullptr, 0);
    k_lstm<<<131072 / 256, 256, 0, stream>>>(gates, hbuf, cbuf, A, A2);
    // htilde = h @ W_attn  (A+1024 holds bf16 h)
    k_gemm<<<dim3(2, 16), 256, 0, stream>>>(A + 1024, 2048, WaT, 1024, 1024, nullptr,
                                            nullptr, 0, htl, 1024, nullptr, 0);
    k_attn<<<128, 512, 0, stream>>>(enc, htl, out + O4 + (size_t)k * (B_ * S_), cenc, A2);
    // ha = [c_enc|h] @ W_out^T + b_out -> output_ slot (f32) + A[:, :1024] (bf16)
    k_gemm<<<dim3(2, 16), 256, 0, stream>>>(A2, 2048, Wo, 2048, 2048, b_out,
                                            nullptr, 0, out + O0 + (size_t)k * H_,
                                            (long long)T_ * H_, A, 2048);
    k_p<<<128, 64, 0, stream>>>(hbuf, cenc, px, W_pt, out, k);
  }
  k_final<<<131072 / 256, 256, 0, stream>>>(hbuf, cbuf, out);
}

// Round 2
// 6025.637 us; speedup vs baseline: 1.3837x; 1.3837x over previous
//
#include <hip/hip_runtime.h>

typedef __attribute__((ext_vector_type(8))) short short8;
typedef __attribute__((ext_vector_type(4))) short short4v;
typedef __attribute__((ext_vector_type(4))) float floatx4;

// ---------------- constants ----------------
#define B_  128
#define T_  32
#define S_  512
#define H_  1024
#define IN_ 1024

// output offsets (f32 elements)
#define O0 0            // output_ [B,T,H]
#define O1 4194304      // h [B,H]
#define O2 4325376      // c [B,H]
#define O3 4456448      // h_attn_out [B,H]
#define O4 4587520      // out_attn [T,B,S]
#define O5 6684672      // past_attn [B,S]
#define O6 6750208      // p_gen [B,T]
#define O7 6754304      // past_dehy [B,1,H]
#define O8 6885376      // loss_cv [1]

__device__ __forceinline__ unsigned short f2bf(float f) {
  unsigned u = __float_as_uint(f);
  u += 0x7fffu + ((u >> 16) & 1u);
  return (unsigned short)(u >> 16);
}
__device__ __forceinline__ float bf2f(unsigned short s) {
  return __uint_as_float(((unsigned)s) << 16);
}
__device__ __forceinline__ float sigmoidf_(float x) { return 1.f / (1.f + __expf(-x)); }

// ---------------- converts ----------------
__global__ void k_conv_direct(const float* __restrict__ src, unsigned short* __restrict__ dst, int n) {
  int i = blockIdx.x * 256 + threadIdx.x;
  if (i < n) dst[i] = f2bf(src[i]);
}
// Wc[n][k]: k<1024 -> W_ih[n][IN+k] (ha part); k>=1024 -> W_hh[n][k-1024]
__global__ void k_conv_Wc(const float* __restrict__ W_ih, const float* __restrict__ W_hh,
                          unsigned short* __restrict__ Wc) {
  int i = blockIdx.x * 256 + threadIdx.x;  // 4096*2048
  int n = i >> 11, k = i & 2047;
  float v = (k < 1024) ? W_ih[(size_t)n * 2048 + 1024 + k] : W_hh[(size_t)n * 1024 + (k - 1024)];
  Wc[i] = f2bf(v);
}
// Wx[n][k] = W_ih[n][k], k<1024
__global__ void k_conv_Wx(const float* __restrict__ W_ih, unsigned short* __restrict__ Wx) {
  int i = blockIdx.x * 256 + threadIdx.x;  // 4096*1024
  int n = i >> 10, k = i & 1023;
  Wx[i] = f2bf(W_ih[(size_t)n * 2048 + k]);
}
// W2[n][0..1024)=Whi, [1024..2048)=Whi, [2048..3072)=Wlo  where Whi/lo split W_attn^T
__global__ void k_conv_W2(const float* __restrict__ W_attn, unsigned short* __restrict__ W2) {
  int i = blockIdx.x * 256 + threadIdx.x;  // 1024*1024
  int n = i >> 10, k = i & 1023;
  float v = W_attn[(size_t)k * 1024 + n];
  unsigned short hi = f2bf(v);
  unsigned short lo = f2bf(v - bf2f(hi));
  size_t base = (size_t)n * 3072 + k;
  W2[base] = hi; W2[base + 1024] = hi; W2[base + 2048] = lo;
}
// enc -> bf16, 4 elems/thread
__global__ void k_conv_enc(const float* __restrict__ src, unsigned short* __restrict__ dst) {
  size_t i = (size_t)(blockIdx.x) * 256 + threadIdx.x;  // 16777216 threads
  floatx4 v = *(const floatx4*)&src[i * 4];
  short4v d;
  d[0] = (short)f2bf(v.x); d[1] = (short)f2bf(v.y);
  d[2] = (short)f2bf(v.z); d[3] = (short)f2bf(v.w);
  *(short4v*)&dst[i * 4] = d;
}

// ---------------- init ----------------
__global__ void k_init(const float* __restrict__ hidden_h, const float* __restrict__ hidden_c,
                       const float* __restrict__ h_attn, const float* __restrict__ past_attn,
                       const float* __restrict__ past_dehy, const float* __restrict__ b_ih,
                       const float* __restrict__ b_hh, unsigned short* __restrict__ A0,
                       float* __restrict__ hbuf, float* __restrict__ cbuf,
                       float* __restrict__ bc, float* __restrict__ out) {
  int i = blockIdx.x * 256 + threadIdx.x;  // 131072 threads
  if (i < B_ * H_) {
    int b = i >> 10, j = i & 1023;
    A0[(size_t)b * 2048 + j] = f2bf(h_attn[i]);
    A0[(size_t)b * 2048 + 1024 + j] = f2bf(hidden_h[i]);
    hbuf[i] = hidden_h[i];
    cbuf[i] = hidden_c[i];
    out[O7 + i] = past_dehy[i];
  }
  if (i < B_ * S_) out[O5 + i] = past_attn[i];
  if (i < 4096) bc[i] = b_ih[i] + b_hh[i];
  if (i == 0) out[O8] = 0.f;
}

// ---------------- px precompute: px[m] = input_[m,:]·W_pt[0:1024] + b_pt ----------------
__global__ __launch_bounds__(64) void k_px(const float* __restrict__ input_,
                                           const float* __restrict__ W_pt,
                                           const float* __restrict__ b_pt,
                                           float* __restrict__ px) {
  int m = blockIdx.x;
  int lane = threadIdx.x;
  const float* x = input_ + (size_t)m * 1024;
  float s = 0.f;
  for (int j = lane; j < 1024; j += 64) s += x[j] * W_pt[j];
  for (int off = 32; off; off >>= 1) s += __shfl_down(s, off);
  if (lane == 0) px[m] = s + b_pt[0];
}

// ---------------- generic bf16 MFMA GEMM: C[M,N] = A[M,K]*B[N,K]^T (+bias), reg-prefetched ----------------
__global__ __launch_bounds__(256) void k_gemm(
    const unsigned short* __restrict__ A, int lda,
    const unsigned short* __restrict__ B, int ldb, int K,
    const float* __restrict__ bias,
    float* __restrict__ outf, long long outfld,
    unsigned short* __restrict__ outb, long long outbld) {
  __shared__ alignas(16) unsigned short As[64][72];
  __shared__ alignas(16) unsigned short Bs[64][72];
  const int m0 = blockIdx.x * 64, n0 = blockIdx.y * 64;
  const int t = threadIdx.x;
  const int lane = t & 63, wid = t >> 6;
  const int wm = wid >> 1, wn = wid & 1;
  const int sr = t >> 2, sk = (t & 3) << 4;
  const int l15 = lane & 15, lhi = lane >> 4;
  floatx4 acc[2][2];
#pragma unroll
  for (int i = 0; i < 2; i++)
#pragma unroll
    for (int j = 0; j < 2; j++) acc[i][j] = (floatx4){0.f, 0.f, 0.f, 0.f};

  const unsigned short* ga = A + (size_t)(m0 + sr) * lda + sk;
  const unsigned short* gb = B + (size_t)(n0 + sr) * ldb + sk;
  short8 ra0 = *(const short8*)ga;
  short8 ra1 = *(const short8*)(ga + 8);
  short8 rb0 = *(const short8*)gb;
  short8 rb1 = *(const short8*)(gb + 8);

  for (int k0 = 0; k0 < K; k0 += 64) {
    *(short8*)&As[sr][sk] = ra0;
    *(short8*)&As[sr][sk + 8] = ra1;
    *(short8*)&Bs[sr][sk] = rb0;
    *(short8*)&Bs[sr][sk + 8] = rb1;
    __syncthreads();
    if (k0 + 64 < K) {
      ra0 = *(const short8*)(ga + k0 + 64);
      ra1 = *(const short8*)(ga + k0 + 72);
      rb0 = *(const short8*)(gb + k0 + 64);
      rb1 = *(const short8*)(gb + k0 + 72);
    }
#pragma unroll
    for (int kk = 0; kk < 64; kk += 32) {
      const int kb = kk + lhi * 8;
      short8 af0 = *(const short8*)&As[wm * 32 + l15][kb];
      short8 af1 = *(const short8*)&As[wm * 32 + 16 + l15][kb];
      short8 bf0 = *(const short8*)&Bs[wn * 32 + l15][kb];
      short8 bf1 = *(const short8*)&Bs[wn * 32 + 16 + l15][kb];
      acc[0][0] = __builtin_amdgcn_mfma_f32_16x16x32_bf16(af0, bf0, acc[0][0], 0, 0, 0);
      acc[0][1] = __builtin_amdgcn_mfma_f32_16x16x32_bf16(af0, bf1, acc[0][1], 0, 0, 0);
      acc[1][0] = __builtin_amdgcn_mfma_f32_16x16x32_bf16(af1, bf0, acc[1][0], 0, 0, 0);
      acc[1][1] = __builtin_amdgcn_mfma_f32_16x16x32_bf16(af1, bf1, acc[1][1], 0, 0, 0);
    }
    __syncthreads();
  }
#pragma unroll
  for (int i = 0; i < 2; i++) {
    const int mb = m0 + wm * 32 + i * 16 + (lhi << 2);
#pragma unroll
    for (int j = 0; j < 2; j++) {
      const int n = n0 + wn * 32 + j * 16 + l15;
      const float bs = bias ? bias[n] : 0.f;
#pragma unroll
      for (int r = 0; r < 4; r++) {
        const int m = mb + r;
        float v = acc[i][j][r] + bs;
        if (outf) outf[(size_t)m * outfld + n] = v;
        if (outb) outb[(size_t)m * outbld + n] = f2bf(v);
      }
    }
  }
}

// ---------------- fused gates GEMM + LSTM elementwise ----------------
// grid (2,16), 256 thr. Block: rows [m0,m0+64), h-cols [n0,n0+64), all 4 gates.
__global__ __launch_bounds__(256) void k_gates(
    const unsigned short* __restrict__ A,   // [128][2048] = [ha|h] (read)
    const unsigned short* __restrict__ Wc,  // [4096][2048]
    const unsigned short* __restrict__ gx,  // [4096][4096] bf16, row b*32+t
    float* __restrict__ hbuf, float* __restrict__ cbuf,
    unsigned short* __restrict__ Aout,      // [128][2048] write h at +1024 (next step's A)
    unsigned short* __restrict__ A2,        // [128][2048] write h at +1024
    unsigned short* __restrict__ Ah,        // [128][3072] = [h_hi|h_lo|h_hi]
    int k) {
  __shared__ alignas(16) unsigned short As[64][72];
  __shared__ alignas(16) unsigned short Bs[256][72];
  const int m0 = blockIdx.x * 64, n0 = blockIdx.y * 64;
  const int t = threadIdx.x, lane = t & 63, w = t >> 6;
  const int l15 = lane & 15, lhi = lane >> 4;
  const int ar = t >> 2, ak = (t & 3) << 4;
  floatx4 acc[4][4];
#pragma unroll
  for (int g = 0; g < 4; g++)
#pragma unroll
    for (int nb = 0; nb < 4; nb++) acc[g][nb] = (floatx4){0.f, 0.f, 0.f, 0.f};

  const unsigned short* ga = A + (size_t)(m0 + ar) * 2048 + ak;
  const unsigned short* gw = Wc + (size_t)(n0 + ar) * 2048 + ak;
  short8 ra0 = *(const short8*)ga;
  short8 ra1 = *(const short8*)(ga + 8);
  short8 rb[4][2];
#pragma unroll
  for (int p = 0; p < 4; p++) {
    const unsigned short* gp = gw + (size_t)p * 1024 * 2048;
    rb[p][0] = *(const short8*)gp;
    rb[p][1] = *(const short8*)(gp + 8);
  }
  for (int k0 = 0; k0 < 2048; k0 += 64) {
    *(short8*)&As[ar][ak] = ra0;
    *(short8*)&As[ar][ak + 8] = ra1;
#pragma unroll
    for (int p = 0; p < 4; p++) {
      *(short8*)&Bs[p * 64 + ar][ak] = rb[p][0];
      *(short8*)&Bs[p * 64 + ar][ak + 8] = rb[p][1];
    }
    __syncthreads();
    if (k0 + 64 < 2048) {
      ra0 = *(const short8*)(ga + k0 + 64);
      ra1 = *(const short8*)(ga + k0 + 72);
#pragma unroll
      for (int p = 0; p < 4; p++) {
        const unsigned short* gp = gw + (size_t)p * 1024 * 2048 + k0 + 64;
        rb[p][0] = *(const short8*)gp;
        rb[p][1] = *(const short8*)(gp + 8);
      }
    }
#pragma unroll
    for (int kk = 0; kk < 64; kk += 32) {
      const int kb = kk + lhi * 8;
      short8 af = *(const short8*)&As[w * 16 + l15][kb];
#pragma unroll
      for (int g = 0; g < 4; g++)
#pragma unroll
        for (int nb = 0; nb < 4; nb++) {
          short8 bfr = *(const short8*)&Bs[g * 64 + nb * 16 + l15][kb];
          acc[g][nb] = __builtin_amdgcn_mfma_f32_16x16x32_bf16(af, bfr, acc[g][nb], 0, 0, 0);
        }
    }
    __syncthreads();
  }
  // epilogue: full LSTM cell in-register
  const int brow = m0 + w * 16 + lhi * 4;
#pragma unroll
  for (int nb = 0; nb < 4; nb++) {
    const int j = n0 + nb * 16 + l15;
#pragma unroll
    for (int r = 0; r < 4; r++) {
      const int bb = brow + r;
      const size_t gxr = ((size_t)(bb * 32 + k)) * 4096 + j;
      float p0 = acc[0][nb][r] + bf2f(gx[gxr]);
      float p1 = acc[1][nb][r] + bf2f(gx[gxr + 1024]);
      float p2 = acc[2][nb][r] + bf2f(gx[gxr + 2048]);
      float p3 = acc[3][nb][r] + bf2f(gx[gxr + 3072]);
      float iv = sigmoidf_(p0), fv = sigmoidf_(p1);
      float gv = tanhf(p2), ov = sigmoidf_(p3);
      const size_t hj = (size_t)bb * 1024 + j;
      float cn = fv * cbuf[hj] + iv * gv;
      float hn = ov * tanhf(cn);
      cbuf[hj] = cn;
      hbuf[hj] = hn;
      unsigned short hi16 = f2bf(hn);
      unsigned short lo16 = f2bf(hn - bf2f(hi16));
      Aout[(size_t)bb * 2048 + 1024 + j] = hi16;
      A2[(size_t)bb * 2048 + 1024 + j] = hi16;
      const size_t ah = (size_t)bb * 3072 + j;
      Ah[ah] = hi16; Ah[ah + 1024] = lo16; Ah[ah + 2048] = hi16;
    }
  }
}

// ---------------- attention (bf16 enc) + fused p_gen ----------------
__global__ __launch_bounds__(512) void k_attn(
    const unsigned short* __restrict__ ebf, const float* __restrict__ htl,
    float* __restrict__ attn_out, unsigned short* __restrict__ A2,
    const float* __restrict__ hbuf, const float* __restrict__ px,
    const float* __restrict__ W_pt, float* __restrict__ out, int k) {
  const int b = blockIdx.x, t = threadIdx.x;
  const int lane = t & 63, wid = t >> 6;  // 8 waves
  __shared__ float logit[512];
  __shared__ float red[16];
  const unsigned short* encb = ebf + (size_t)b * (S_ * H_);
  // htilde slice for this lane's 16 columns
  float htf[16];
#pragma unroll
  for (int q = 0; q < 4; q++) {
    floatx4 hv = *(const floatx4*)&htl[(size_t)b * 1024 + lane * 16 + q * 4];
    htf[q * 4 + 0] = hv.x; htf[q * 4 + 1] = hv.y;
    htf[q * 4 + 2] = hv.z; htf[q * 4 + 3] = hv.w;
  }
  // phase 1: logits, wave per s
  for (int s = wid; s < S_; s += 8) {
    const unsigned short* row = encb + (size_t)s * H_ + lane * 16;
    short8 e0 = *(const short8*)row;
    short8 e1 = *(const short8*)(row + 8);
    float sum = 0.f;
#pragma unroll
    for (int i = 0; i < 8; i++) sum += bf2f((unsigned short)e0[i]) * htf[i];
#pragma unroll
    for (int i = 0; i < 8; i++) sum += bf2f((unsigned short)e1[i]) * htf[8 + i];
    for (int off = 32; off; off >>= 1) sum += __shfl_down(sum, off);
    if (lane == 0) logit[s] = sum;
  }
  __syncthreads();
  // phase 2: softmax over 512
  float x = logit[t];
  float mx = x;
  for (int off = 32; off; off >>= 1) mx = fmaxf(mx, __shfl_xor(mx, off));
  if (lane == 0) red[wid] = mx;
  __syncthreads();
  float M = red[0];
#pragma unroll
  for (int w = 1; w < 8; w++) M = fmaxf(M, red[w]);
  float e = __expf(x - M);
  float sm = e;
  for (int off = 32; off; off >>= 1) sm += __shfl_xor(sm, off);
  if (lane == 0) red[8 + wid] = sm;
  __syncthreads();
  float L = 0.f;
#pragma unroll
  for (int w = 0; w < 8; w++) L += red[8 + w];
  float at = e / L;
  logit[t] = at;
  attn_out[(size_t)b * S_ + t] = at;
  __syncthreads();
  // phase 3: c_enc cols {2t, 2t+1}
  const unsigned short* col = encb + 2 * t;
  float a0 = 0.f, a1 = 0.f, c0 = 0.f, c1 = 0.f;
#pragma unroll 4
  for (int s = 0; s < S_; s += 2) {
    unsigned v0 = *(const unsigned*)(col + (size_t)s * H_);
    unsigned v1 = *(const unsigned*)(col + (size_t)(s + 1) * H_);
    float w0 = logit[s], w1 = logit[s + 1];
    a0 = fmaf(w0, __uint_as_float(v0 << 16), a0);
    a1 = fmaf(w0, __uint_as_float(v0 & 0xffff0000u), a1);
    c0 = fmaf(w1, __uint_as_float(v1 << 16), c0);
    c1 = fmaf(w1, __uint_as_float(v1 & 0xffff0000u), c1);
  }
  a0 += c0; a1 += c1;
  unsigned pack = (unsigned)f2bf(a0) | ((unsigned)f2bf(a1) << 16);
  *(unsigned*)&A2[(size_t)b * 2048 + 2 * t] = pack;
  // fused p_gen: h·wh + cenc·wc (x part precomputed in px)
  float pp = a0 * W_pt[2048 + 2 * t] + a1 * W_pt[2049 + 2 * t] +
             hbuf[(size_t)b * 1024 + 2 * t] * W_pt[1024 + 2 * t] +
             hbuf[(size_t)b * 1024 + 2 * t + 1] * W_pt[1025 + 2 * t];
  for (int off = 32; off; off >>= 1) pp += __shfl_down(pp, off);
  if (lane == 0) red[wid] = pp;
  __syncthreads();
  if (t == 0) {
    float sp = 0.f;
#pragma unroll
    for (int w = 0; w < 8; w++) sp += red[w];
    out[O6 + b * T_ + k] = sigmoidf_(sp + px[b * T_ + k]);
  }
}

// ---------------- finalize ----------------
__global__ void k_final(const float* __restrict__ hbuf, const float* __restrict__ cbuf,
                        float* __restrict__ out) {
  int i = blockIdx.x * 256 + threadIdx.x;  // B*H
  out[O1 + i] = hbuf[i];
  out[O2 + i] = cbuf[i];
  int b = i >> 10, j = i & 1023;
  out[O3 + i] = out[O0 + (size_t)b * (T_ * H_) + 31 * H_ + j];
}

// ---------------- host ----------------
extern "C" void kernel_launch(void* const* d_in, const int* in_sizes, int n_in,
                              void* d_out, int out_size, void* d_ws, size_t ws_size,
                              hipStream_t stream) {
  const float* input_ = (const float*)d_in[1];
  const float* hidden_h = (const float*)d_in[2];
  const float* hidden_c = (const float*)d_in[3];
  const float* h_attn = (const float*)d_in[4];
  const float* enc = (const float*)d_in[5];
  const float* past_attn = (const float*)d_in[6];
  const float* past_dehy = (const float*)d_in[8];
  const float* W_ih = (const float*)d_in[9];
  const float* b_ih = (const float*)d_in[10];
  const float* W_hh = (const float*)d_in[11];
  const float* b_hh = (const float*)d_in[12];
  const float* W_attn = (const float*)d_in[13];
  const float* W_out = (const float*)d_in[14];
  const float* b_out = (const float*)d_in[15];
  const float* W_pt = (const float*)d_in[16];
  const float* b_pt = (const float*)d_in[17];
  float* out = (float*)d_out;
  char* ws = (char*)d_ws;

  // workspace layout (bytes)
  unsigned short* Wc = (unsigned short*)(ws + 0);             // [4096][2048]
  unsigned short* Wx = (unsigned short*)(ws + 16777216);      // [4096][1024]
  unsigned short* W2 = (unsigned short*)(ws + 25165824);      // [1024][3072]
  unsigned short* Wo = (unsigned short*)(ws + 31457280);      // [1024][2048]
  unsigned short* Xb = (unsigned short*)(ws + 35651584);      // [4096][1024]
  unsigned short* gx = (unsigned short*)(ws + 44040192);      // [4096][4096]
  unsigned short* ebf = (unsigned short*)(ws + 77594624);     // [128][512][1024]
  float* bc = (float*)(ws + 211812352);                       // [4096]
  float* px = (float*)(ws + 211828736);                       // [4096]
  unsigned short* A0 = (unsigned short*)(ws + 211845120);     // [128][2048]
  unsigned short* A1 = (unsigned short*)(ws + 212369408);     // [128][2048]
  unsigned short* A2 = (unsigned short*)(ws + 212893696);     // [128][2048] = [cenc|h]
  unsigned short* Ah = (unsigned short*)(ws + 213417984);     // [128][3072]
  float* hbuf = (float*)(ws + 214204416);                     // [128][1024]
  float* cbuf = (float*)(ws + 214728704);
  float* htl = (float*)(ws + 215252992);

  // ---- precompute ----
  k_conv_Wc<<<4096 * 2048 / 256, 256, 0, stream>>>(W_ih, W_hh, Wc);
  k_conv_Wx<<<4096 * 1024 / 256, 256, 0, stream>>>(W_ih, Wx);
  k_conv_W2<<<1024 * 1024 / 256, 256, 0, stream>>>(W_attn, W2);
  k_conv_direct<<<1024 * 2048 / 256, 256, 0, stream>>>(W_out, Wo, 1024 * 2048);
  k_conv_direct<<<4096 * 1024 / 256, 256, 0, stream>>>(input_, Xb, 4096 * 1024);
  k_conv_enc<<<65536, 256, 0, stream>>>(enc, ebf);
  k_init<<<131072 / 256, 256, 0, stream>>>(hidden_h, hidden_c, h_attn, past_attn, past_dehy,
                                           b_ih, b_hh, A0, hbuf, cbuf, bc, out);
  k_px<<<4096, 64, 0, stream>>>(input_, W_pt, b_pt, px);
  // gx = Xb @ Wx^T + bc
  k_gemm<<<dim3(64, 64), 256, 0, stream>>>(Xb, 1024, Wx, 1024, 1024, bc,
                                           nullptr, 0, gx, 4096);

  // ---- recurrent loop ----
  for (int k = 0; k < T_; k++) {
    unsigned short* Acur = (k & 1) ? A1 : A0;
    unsigned short* Anxt = (k & 1) ? A0 : A1;
    k_gates<<<dim3(2, 16), 256, 0, stream>>>(Acur, Wc, gx, hbuf, cbuf, Anxt, A2, Ah, k);
    // htilde = h @ W_attn, hi/lo split K=3072, f32 out
    k_gemm<<<dim3(2, 16), 256, 0, stream>>>(Ah, 3072, W2, 3072, 3072, nullptr,
                                            htl, 1024, nullptr, 0);
    k_attn<<<128, 512, 0, stream>>>(ebf, htl, out + O4 + (size_t)k * (B_ * S_), A2,
                                    hbuf, px, W_pt, out, k);
    // ha = [cenc|h] @ W_out^T + b_out -> output_ (f32) + Anxt[:, :1024] (bf16)
    k_gemm<<<dim3(2, 16), 256, 0, stream>>>(A2, 2048, Wo, 2048, 2048, b_out,
                                            out + O0 + (size_t)k * H_, (long long)(T_ * H_),
                                            Anxt, 2048);
  }
  k_final<<<131072 / 256, 256, 0, stream>>>(hbuf, cbuf, out);
}

// Round 8
// 4741.269 us; speedup vs baseline: 1.7585x; 1.2709x over previous
//
#include <hip/hip_runtime.h>

typedef __attribute__((ext_vector_type(8))) short short8;
typedef __attribute__((ext_vector_type(4))) short short4v;
typedef __attribute__((ext_vector_type(4))) float floatx4;

// ---------------- constants ----------------
#define B_  128
#define T_  32
#define S_  512
#define H_  1024
#define IN_ 1024

// output offsets (f32 elements)
#define O0 0            // output_ [B,T,H]
#define O1 4194304      // h [B,H]
#define O2 4325376      // c [B,H]
#define O3 4456448      // h_attn_out [B,H]
#define O4 4587520      // out_attn [T,B,S]
#define O5 6684672      // past_attn [B,S]
#define O6 6750208      // p_gen [B,T]
#define O7 6754304      // past_dehy [B,1,H]
#define O8 6885376      // loss_cv [1]

__device__ __forceinline__ unsigned short f2bf(float f) {
  unsigned u = __float_as_uint(f);
  u += 0x7fffu + ((u >> 16) & 1u);
  return (unsigned short)(u >> 16);
}
__device__ __forceinline__ float bf2f(unsigned short s) {
  return __uint_as_float(((unsigned)s) << 16);
}
__device__ __forceinline__ float sigmoidf_(float x) { return 1.f / (1.f + __expf(-x)); }

// ---------------- converts ----------------
__global__ void k_conv_direct(const float* __restrict__ src, unsigned short* __restrict__ dst, int n) {
  int i = blockIdx.x * 256 + threadIdx.x;
  if (i < n) dst[i] = f2bf(src[i]);
}
// Wc[n][k]: k<1024 -> W_ih[n][IN+k]; k>=1024 -> W_hh[n][k-1024]  (step-0 weights)
__global__ void k_conv_Wc(const float* __restrict__ W_ih, const float* __restrict__ W_hh,
                          unsigned short* __restrict__ Wc) {
  int i = blockIdx.x * 256 + threadIdx.x;  // 4096*2048
  int n = i >> 11, k = i & 2047;
  float v = (k < 1024) ? W_ih[(size_t)n * 2048 + 1024 + k] : W_hh[(size_t)n * 1024 + (k - 1024)];
  Wc[i] = f2bf(v);
}
// Wx[n][k] = W_ih[n][k]  (input part)
__global__ void k_conv_Wx(const float* __restrict__ W_ih, unsigned short* __restrict__ Wx) {
  int i = blockIdx.x * 256 + threadIdx.x;  // 4096*1024
  int n = i >> 10, k = i & 1023;
  Wx[i] = f2bf(W_ih[(size_t)n * 2048 + k]);
}
// Wa[n][a] = W_ih[n][1024+a]  (ha part)
__global__ void k_conv_Wa(const float* __restrict__ W_ih, unsigned short* __restrict__ Wa) {
  int i = blockIdx.x * 256 + threadIdx.x;  // 4096*1024
  int n = i >> 10, a = i & 1023;
  Wa[i] = f2bf(W_ih[(size_t)n * 2048 + 1024 + a]);
}
// WocT[j][a] = W_out[a][j]; WohT[j][a] = W_out[a][1024+j]
__global__ void k_conv_WoT(const float* __restrict__ W_out, unsigned short* __restrict__ WocT,
                           unsigned short* __restrict__ WohT) {
  int i = blockIdx.x * 256 + threadIdx.x;  // 1024*1024
  int j = i >> 10, a = i & 1023;
  WocT[i] = f2bf(W_out[(size_t)a * 2048 + j]);
  WohT[i] = f2bf(W_out[(size_t)a * 2048 + 1024 + j]);
}
// W2[n][0..1024)=Whi, [1024..2048)=Whi, [2048..3072)=Wlo  (hi/lo split of W_attn^T)
__global__ void k_conv_W2(const float* __restrict__ W_attn, unsigned short* __restrict__ W2) {
  int i = blockIdx.x * 256 + threadIdx.x;  // 1024*1024
  int n = i >> 10, k = i & 1023;
  float v = W_attn[(size_t)k * 1024 + n];
  unsigned short hi = f2bf(v);
  unsigned short lo = f2bf(v - bf2f(hi));
  size_t base = (size_t)n * 3072 + k;
  W2[base] = hi; W2[base + 1024] = hi; W2[base + 2048] = lo;
}
// Xb[t*128+b][c] = input_[b][t][c]
__global__ void k_conv_Xb(const float* __restrict__ input_, unsigned short* __restrict__ Xb) {
  int i = blockIdx.x * 256 + threadIdx.x;  // 4096*1024
  int mp = i >> 10, c = i & 1023;
  int t = mp >> 7, b = mp & 127;
  Xb[i] = f2bf(input_[((size_t)b * 32 + t) * 1024 + c]);
}
// enc -> bf16
__global__ void k_conv_enc(const float* __restrict__ src, unsigned short* __restrict__ dst) {
  size_t i = (size_t)(blockIdx.x) * 256 + threadIdx.x;  // 16777216 threads
  floatx4 v = *(const floatx4*)&src[i * 4];
  short4v d;
  d[0] = (short)f2bf(v.x); d[1] = (short)f2bf(v.y);
  d[2] = (short)f2bf(v.z); d[3] = (short)f2bf(v.w);
  *(short4v*)&dst[i * 4] = d;
}
// fuse Wg: [n][k2<1024]=Wpcf ; [k2>=1024]=Wphf + W_hh
__global__ void k_fuse_Wg(const float* __restrict__ Wpcf, const float* __restrict__ Wphf,
                          const float* __restrict__ W_hh, unsigned short* __restrict__ Wg) {
  int i = blockIdx.x * 256 + threadIdx.x;  // 4096*2048
  int n = i >> 11, k2 = i & 2047;
  float v = (k2 < 1024) ? Wpcf[(size_t)n * 1024 + k2]
                        : (Wphf[(size_t)n * 1024 + (k2 - 1024)] + W_hh[(size_t)n * 1024 + (k2 - 1024)]);
  Wg[i] = f2bf(v);
}
// bg[n] = sum_a b_out[a] * W_ih[n][1024+a]
__global__ __launch_bounds__(64) void k_bg(const float* __restrict__ W_ih,
                                           const float* __restrict__ b_out,
                                           float* __restrict__ bg) {
  int n = blockIdx.x, lane = threadIdx.x;
  const float* row = W_ih + (size_t)n * 2048 + 1024;
  float s = 0.f;
  for (int a = lane; a < 1024; a += 64) s += b_out[a] * row[a];
  for (int off = 32; off; off >>= 1) s += __shfl_down(s, off);
  if (lane == 0) bg[n] = s;
}

// ---------------- init ----------------
__global__ void k_init(const float* __restrict__ hidden_h, const float* __restrict__ hidden_c,
                       const float* __restrict__ h_attn, const float* __restrict__ past_attn,
                       const float* __restrict__ past_dehy, const float* __restrict__ b_ih,
                       const float* __restrict__ b_hh, unsigned short* __restrict__ A0,
                       float* __restrict__ hbuf, float* __restrict__ cbuf,
                       float* __restrict__ bc, float* __restrict__ out) {
  int i = blockIdx.x * 256 + threadIdx.x;  // 131072 threads
  if (i < B_ * H_) {
    int b = i >> 10, j = i & 1023;
    A0[(size_t)b * 2048 + j] = f2bf(h_attn[i]);
    A0[(size_t)b * 2048 + 1024 + j] = f2bf(hidden_h[i]);
    hbuf[i] = hidden_h[i];
    cbuf[i] = hidden_c[i];
    out[O7 + i] = past_dehy[i];
  }
  if (i < B_ * S_) out[O5 + i] = past_attn[i];
  if (i < 4096) bc[i] = b_ih[i] + b_hh[i];
  if (i == 0) out[O8] = 0.f;
}

// ---------------- px: px[m=b*32+t] = input_[m,:]·W_pt[0:1024] + b_pt ----------------
__global__ __launch_bounds__(64) void k_px(const float* __restrict__ input_,
                                           const float* __restrict__ W_pt,
                                           const float* __restrict__ b_pt,
                                           float* __restrict__ px) {
  int m = blockIdx.x, lane = threadIdx.x;
  const float* x = input_ + (size_t)m * 1024;
  float s = 0.f;
  for (int j = lane; j < 1024; j += 64) s += x[j] * W_pt[j];
  for (int off = 32; off; off >>= 1) s += __shfl_down(s, off);
  if (lane == 0) px[m] = s + b_pt[0];
}

// ---------------- generic bf16 MFMA GEMM: C[M,N] = A[M,K]*B[N,K]^T (+bias) ----------------
__global__ __launch_bounds__(256) void k_gemm(
    const unsigned short* __restrict__ A, long long lda,
    const unsigned short* __restrict__ B, int ldb, int K,
    const float* __restrict__ bias,
    float* __restrict__ outf, long long outfld,
    unsigned short* __restrict__ outb, long long outbld) {
  __shared__ alignas(16) unsigned short As[64][72];
  __shared__ alignas(16) unsigned short Bs[64][72];
  const int m0 = blockIdx.x * 64, n0 = blockIdx.y * 64;
  const int t = threadIdx.x;
  const int lane = t & 63, wid = t >> 6;
  const int wm = wid >> 1, wn = wid & 1;
  const int sr = t >> 2, sk = (t & 3) << 4;
  const int l15 = lane & 15, lhi = lane >> 4;
  floatx4 acc[2][2];
#pragma unroll
  for (int i = 0; i < 2; i++)
#pragma unroll
    for (int j = 0; j < 2; j++) acc[i][j] = (floatx4){0.f, 0.f, 0.f, 0.f};

  const unsigned short* ga = A + (size_t)(m0 + sr) * lda + sk;
  const unsigned short* gb = B + (size_t)(n0 + sr) * ldb + sk;
  short8 ra0 = *(const short8*)ga;
  short8 ra1 = *(const short8*)(ga + 8);
  short8 rb0 = *(const short8*)gb;
  short8 rb1 = *(const short8*)(gb + 8);

  for (int k0 = 0; k0 < K; k0 += 64) {
    *(short8*)&As[sr][sk] = ra0;
    *(short8*)&As[sr][sk + 8] = ra1;
    *(short8*)&Bs[sr][sk] = rb0;
    *(short8*)&Bs[sr][sk + 8] = rb1;
    __syncthreads();
    if (k0 + 64 < K) {
      ra0 = *(const short8*)(ga + k0 + 64);
      ra1 = *(const short8*)(ga + k0 + 72);
      rb0 = *(const short8*)(gb + k0 + 64);
      rb1 = *(const short8*)(gb + k0 + 72);
    }
#pragma unroll
    for (int kk = 0; kk < 64; kk += 32) {
      const int kb = kk + lhi * 8;
      short8 af0 = *(const short8*)&As[wm * 32 + l15][kb];
      short8 af1 = *(const short8*)&As[wm * 32 + 16 + l15][kb];
      short8 bf0 = *(const short8*)&Bs[wn * 32 + l15][kb];
      short8 bf1 = *(const short8*)&Bs[wn * 32 + 16 + l15][kb];
      acc[0][0] = __builtin_amdgcn_mfma_f32_16x16x32_bf16(af0, bf0, acc[0][0], 0, 0, 0);
      acc[0][1] = __builtin_amdgcn_mfma_f32_16x16x32_bf16(af0, bf1, acc[0][1], 0, 0, 0);
      acc[1][0] = __builtin_amdgcn_mfma_f32_16x16x32_bf16(af1, bf0, acc[1][0], 0, 0, 0);
      acc[1][1] = __builtin_amdgcn_mfma_f32_16x16x32_bf16(af1, bf1, acc[1][1], 0, 0, 0);
    }
    __syncthreads();
  }
#pragma unroll
  for (int i = 0; i < 2; i++) {
    const int mb = m0 + wm * 32 + i * 16 + (lhi << 2);
#pragma unroll
    for (int j = 0; j < 2; j++) {
      const int n = n0 + wn * 32 + j * 16 + l15;
      const float bs = bias ? bias[n] : 0.f;
#pragma unroll
      for (int r = 0; r < 4; r++) {
        const int m = mb + r;
        float v = acc[i][j][r] + bs;
        if (outf) outf[(size_t)m * outfld + n] = v;
        if (outb) outb[(size_t)m * outbld + n] = f2bf(v);
      }
    }
  }
}

// ---------------- fused gates GEMM + LSTM elementwise ----------------
// grid (2, 32): m-tile 64 (b), j-tile 32, all 4 gates.
__global__ __launch_bounds__(256) void k_gates(
    const unsigned short* __restrict__ A, long long lda,   // [..][2048] bf16
    const unsigned short* __restrict__ W,                  // [4096][2048] bf16
    const float* __restrict__ gxf,                         // rows t*128+b, [4096] f32
    const float* __restrict__ bg,                          // optional [4096]
    float* __restrict__ hbuf, float* __restrict__ cbuf,
    unsigned short* __restrict__ Asq,                      // [4096][2048] rows b*32+t
    unsigned short* __restrict__ Ah,                       // [128][3072] = [h_hi|h_lo|h_hi]
    int k) {
  __shared__ alignas(16) unsigned short As[64][72];
  __shared__ alignas(16) unsigned short Bs[128][72];
  const int m0 = blockIdx.x * 64;
  const int j0 = blockIdx.y * 32;
  const int t = threadIdx.x, lane = t & 63, w = t >> 6;
  const int l15 = lane & 15, lhi = lane >> 4;
  const int ar = t >> 2, ak = (t & 3) << 4;
  const int wr = t >> 1, wk = (t & 1) << 5;
  const int gg = wr >> 5, jj = wr & 31;
  floatx4 acc[4][2];
#pragma unroll
  for (int g = 0; g < 4; g++)
#pragma unroll
    for (int jf = 0; jf < 2; jf++) acc[g][jf] = (floatx4){0.f, 0.f, 0.f, 0.f};

  const unsigned short* ga = A + (size_t)(m0 + ar) * lda + ak;
  const unsigned short* gb = W + (size_t)(gg * 1024 + j0 + jj) * 2048 + wk;
  short8 ra0 = *(const short8*)ga;
  short8 ra1 = *(const short8*)(ga + 8);
  short8 rb0 = *(const short8*)gb;
  short8 rb1 = *(const short8*)(gb + 8);
  short8 rb2 = *(const short8*)(gb + 16);
  short8 rb3 = *(const short8*)(gb + 24);

  for (int k0 = 0; k0 < 2048; k0 += 64) {
    *(short8*)&As[ar][ak] = ra0;
    *(short8*)&As[ar][ak + 8] = ra1;
    *(short8*)&Bs[wr][wk] = rb0;
    *(short8*)&Bs[wr][wk + 8] = rb1;
    *(short8*)&Bs[wr][wk + 16] = rb2;
    *(short8*)&Bs[wr][wk + 24] = rb3;
    __syncthreads();
    if (k0 + 64 < 2048) {
      ra0 = *(const short8*)(ga + k0 + 64);
      ra1 = *(const short8*)(ga + k0 + 72);
      rb0 = *(const short8*)(gb + k0 + 64);
      rb1 = *(const short8*)(gb + k0 + 72);
      rb2 = *(const short8*)(gb + k0 + 80);
      rb3 = *(const short8*)(gb + k0 + 88);
    }
#pragma unroll
    for (int kk = 0; kk < 64; kk += 32) {
      const int kb = kk + lhi * 8;
      short8 af = *(const short8*)&As[w * 16 + l15][kb];
#pragma unroll
      for (int g = 0; g < 4; g++)
#pragma unroll
        for (int jf = 0; jf < 2; jf++) {
          short8 bfr = *(const short8*)&Bs[g * 32 + jf * 16 + l15][kb];
          acc[g][jf] = __builtin_amdgcn_mfma_f32_16x16x32_bf16(af, bfr, acc[g][jf], 0, 0, 0);
        }
    }
    __syncthreads();
  }
  const int mb = m0 + w * 16 + lhi * 4;
#pragma unroll
  for (int jf = 0; jf < 2; jf++) {
    const int j = j0 + jf * 16 + l15;
    const float bg0 = bg ? bg[j] : 0.f;
    const float bg1 = bg ? bg[1024 + j] : 0.f;
    const float bg2 = bg ? bg[2048 + j] : 0.f;
    const float bg3 = bg ? bg[3072 + j] : 0.f;
#pragma unroll
    for (int r = 0; r < 4; r++) {
      const int bb = mb + r;
      const size_t gxr = ((size_t)(k * 128 + bb)) * 4096 + j;
      float p0 = acc[0][jf][r] + gxf[gxr] + bg0;
      float p1 = acc[1][jf][r] + gxf[gxr + 1024] + bg1;
      float p2 = acc[2][jf][r] + gxf[gxr + 2048] + bg2;
      float p3 = acc[3][jf][r] + gxf[gxr + 3072] + bg3;
      float iv = sigmoidf_(p0), fv = sigmoidf_(p1);
      float gv = tanhf(p2), ov = sigmoidf_(p3);
      const size_t hj = (size_t)bb * 1024 + j;
      float cn = fv * cbuf[hj] + iv * gv;
      float hn = ov * tanhf(cn);
      cbuf[hj] = cn;
      hbuf[hj] = hn;
      unsigned short hi16 = f2bf(hn);
      unsigned short lo16 = f2bf(hn - bf2f(hi16));
      Asq[((size_t)bb * 32 + k) * 2048 + 1024 + j] = hi16;
      const size_t ah = (size_t)bb * 3072 + j;
      Ah[ah] = hi16; Ah[ah + 1024] = lo16; Ah[ah + 2048] = hi16;
    }
  }
}

// ---------------- attention (f32 htilde vs bf16 enc) + fused p_gen ----------------
__global__ __launch_bounds__(512) void k_attn(
    const unsigned short* __restrict__ ebf, const float* __restrict__ htl,
    const float* __restrict__ hbuf, const float* __restrict__ px,
    const float* __restrict__ W_pt, float* __restrict__ out,
    unsigned short* __restrict__ Asq, float* __restrict__ attn_out, int k) {
  const int b = blockIdx.x, t = threadIdx.x;
  const int lane = t & 63, wid = t >> 6;  // 8 waves
  __shared__ float logit[512];
  __shared__ float red[16];
  const unsigned short* encb = ebf + (size_t)b * (S_ * H_);
  // htilde slice for this lane's 16 columns (f32)
  float htf[16];
#pragma unroll
  for (int q = 0; q < 4; q++) {
    floatx4 hv = *(const floatx4*)&htl[(size_t)b * 1024 + lane * 16 + q * 4];
    htf[q * 4 + 0] = hv.x; htf[q * 4 + 1] = hv.y;
    htf[q * 4 + 2] = hv.z; htf[q * 4 + 3] = hv.w;
  }
  // phase 1: logits, wave per s
  for (int s = wid; s < S_; s += 8) {
    const unsigned short* row = encb + (size_t)s * H_ + lane * 16;
    short8 e0 = *(const short8*)row;
    short8 e1 = *(const short8*)(row + 8);
    float sum = 0.f;
#pragma unroll
    for (int i = 0; i < 8; i++) sum += bf2f((unsigned short)e0[i]) * htf[i];
#pragma unroll
    for (int i = 0; i < 8; i++) sum += bf2f((unsigned short)e1[i]) * htf[8 + i];
    for (int off = 32; off; off >>= 1) sum += __shfl_down(sum, off);
    if (lane == 0) logit[s] = sum;
  }
  __syncthreads();
  // phase 2: softmax over 512
  float x = logit[t];
  float mx = x;
  for (int off = 32; off; off >>= 1) mx = fmaxf(mx, __shfl_xor(mx, off));
  if (lane == 0) red[wid] = mx;
  __syncthreads();
  float M = red[0];
#pragma unroll
  for (int w = 1; w < 8; w++) M = fmaxf(M, red[w]);
  float e = __expf(x - M);
  float sm = e;
  for (int off = 32; off; off >>= 1) sm += __shfl_xor(sm, off);
  if (lane == 0) red[8 + wid] = sm;
  __syncthreads();
  float L = 0.f;
#pragma unroll
  for (int w = 0; w < 8; w++) L += red[8 + w];
  float at = e / L;
  logit[t] = at;
  attn_out[(size_t)b * S_ + t] = at;
  __syncthreads();
  // phase 3: c_enc cols {2t, 2t+1} over bf16 enc
  const unsigned short* col = encb + 2 * t;
  float a0 = 0.f, a1 = 0.f, c0 = 0.f, c1 = 0.f;
#pragma unroll 4
  for (int s = 0; s < S_; s += 2) {
    unsigned v0 = *(const unsigned*)(col + (size_t)s * H_);
    unsigned v1 = *(const unsigned*)(col + (size_t)(s + 1) * H_);
    float w0 = logit[s], w1 = logit[s + 1];
    a0 = fmaf(w0, __uint_as_float(v0 << 16), a0);
    a1 = fmaf(w0, __uint_as_float(v0 & 0xffff0000u), a1);
    c0 = fmaf(w1, __uint_as_float(v1 << 16), c0);
    c1 = fmaf(w1, __uint_as_float(v1 & 0xffff0000u), c1);
  }
  a0 += c0; a1 += c1;
  unsigned pack = (unsigned)f2bf(a0) | ((unsigned)f2bf(a1) << 16);
  *(unsigned*)&Asq[((size_t)b * 32 + k) * 2048 + 2 * t] = pack;
  // fused p_gen
  float pp = a0 * W_pt[2048 + 2 * t] + a1 * W_pt[2049 + 2 * t] +
             hbuf[(size_t)b * 1024 + 2 * t] * W_pt[1024 + 2 * t] +
             hbuf[(size_t)b * 1024 + 2 * t + 1] * W_pt[1025 + 2 * t];
  for (int off = 32; off; off >>= 1) pp += __shfl_down(pp, off);
  if (lane == 0) red[wid] = pp;
  __syncthreads();
  if (t == 0) {
    float sp = 0.f;
#pragma unroll
    for (int w = 0; w < 8; w++) sp += red[w];
    out[O6 + b * T_ + k] = sigmoidf_(sp + px[b * T_ + k]);
  }
}

// ---------------- finalize ----------------
__global__ void k_final(const float* __restrict__ hbuf, const float* __restrict__ cbuf,
                        float* __restrict__ out) {
  int i = blockIdx.x * 256 + threadIdx.x;  // B*H
  out[O1 + i] = hbuf[i];
  out[O2 + i] = cbuf[i];
  int b = i >> 10, j = i & 1023;
  out[O3 + i] = out[O0 + (size_t)b * (T_ * H_) + 31 * H_ + j];
}

// ---------------- host ----------------
extern "C" void kernel_launch(void* const* d_in, const int* in_sizes, int n_in,
                              void* d_out, int out_size, void* d_ws, size_t ws_size,
                              hipStream_t stream) {
  const float* input_ = (const float*)d_in[1];
  const float* hidden_h = (const float*)d_in[2];
  const float* hidden_c = (const float*)d_in[3];
  const float* h_attn = (const float*)d_in[4];
  const float* enc = (const float*)d_in[5];
  const float* past_attn = (const float*)d_in[6];
  const float* past_dehy = (const float*)d_in[8];
  const float* W_ih = (const float*)d_in[9];
  const float* b_ih = (const float*)d_in[10];
  const float* W_hh = (const float*)d_in[11];
  const float* b_hh = (const float*)d_in[12];
  const float* W_attn = (const float*)d_in[13];
  const float* W_out = (const float*)d_in[14];
  const float* b_out = (const float*)d_in[15];
  const float* W_pt = (const float*)d_in[16];
  const float* b_pt = (const float*)d_in[17];
  float* out = (float*)d_out;
  char* ws = (char*)d_ws;

  // workspace layout (bytes)
  unsigned short* Wc   = (unsigned short*)(ws + 0);          // [4096][2048]
  unsigned short* Wx   = (unsigned short*)(ws + 16777216);   // [4096][1024]
  unsigned short* Wa   = (unsigned short*)(ws + 25165824);   // [4096][1024]
  unsigned short* WocT = (unsigned short*)(ws + 33554432);   // [1024][1024]
  unsigned short* WohT = (unsigned short*)(ws + 35651584);   // [1024][1024]
  unsigned short* W2   = (unsigned short*)(ws + 37748736);   // [1024][3072]
  unsigned short* Wo   = (unsigned short*)(ws + 44040192);   // [1024][2048]
  unsigned short* Wg   = (unsigned short*)(ws + 48234496);   // [4096][2048]
  float* Wpcf          = (float*)(ws + 65011712);            // [4096][1024]
  float* Wphf          = (float*)(ws + 81788928);            // [4096][1024]
  unsigned short* Xb   = (unsigned short*)(ws + 98566144);   // [4096][1024] rows t*128+b
  float* gxf           = (float*)(ws + 106954752);           // [4096][4096] rows t*128+b
  unsigned short* ebf  = (unsigned short*)(ws + 174063616);  // [128][512][1024]
  float* bc            = (float*)(ws + 308281344);           // [4096]
  float* bg            = (float*)(ws + 308297728);           // [4096]
  float* px            = (float*)(ws + 308314112);           // [4096]
  unsigned short* A0   = (unsigned short*)(ws + 308330496);  // [128][2048]
  unsigned short* Asq  = (unsigned short*)(ws + 308854784);  // [4096][2048] rows b*32+t
  unsigned short* Ah   = (unsigned short*)(ws + 325632000);  // [128][3072]
  float* hbuf          = (float*)(ws + 326418432);           // [128][1024]
  float* cbuf          = (float*)(ws + 326942720);           // [128][1024]
  float* htl           = (float*)(ws + 327467008);           // [128][1024]

  // ---- conversions ----
  k_conv_Wc<<<32768, 256, 0, stream>>>(W_ih, W_hh, Wc);
  k_conv_Wx<<<16384, 256, 0, stream>>>(W_ih, Wx);
  k_conv_Wa<<<16384, 256, 0, stream>>>(W_ih, Wa);
  k_conv_WoT<<<4096, 256, 0, stream>>>(W_out, WocT, WohT);
  k_conv_W2<<<4096, 256, 0, stream>>>(W_attn, W2);
  k_conv_direct<<<8192, 256, 0, stream>>>(W_out, Wo, 1024 * 2048);
  k_conv_Xb<<<16384, 256, 0, stream>>>(input_, Xb);
  k_conv_enc<<<65536, 256, 0, stream>>>(enc, ebf);
  k_bg<<<4096, 64, 0, stream>>>(W_ih, b_out, bg);
  k_init<<<512, 256, 0, stream>>>(hidden_h, hidden_c, h_attn, past_attn, past_dehy,
                                  b_ih, b_hh, A0, hbuf, cbuf, bc, out);
  k_px<<<4096, 64, 0, stream>>>(input_, W_pt, b_pt, px);

  // ---- folded weights: Wg = [W_iha·Woc | W_iha·Woh + W_hh] ----
  k_gemm<<<dim3(64, 16), 256, 0, stream>>>(Wa, 1024, WocT, 1024, 1024, nullptr,
                                           Wpcf, 1024, nullptr, 0);
  k_gemm<<<dim3(64, 16), 256, 0, stream>>>(Wa, 1024, WohT, 1024, 1024, nullptr,
                                           Wphf, 1024, nullptr, 0);
  k_fuse_Wg<<<32768, 256, 0, stream>>>(Wpcf, Wphf, W_hh, Wg);

  // gxf = Xb @ Wx^T + bc  (f32, rows t*128+b)  — N = 4096! (round-3/4 bug: grid.y was 16)
  k_gemm<<<dim3(64, 64), 256, 0, stream>>>(Xb, 1024, Wx, 1024, 1024, bc,
                                           gxf, 4096, nullptr, 0);

  // ---- recurrent loop: 3 kernels per step ----
  for (int k = 0; k < T_; k++) {
    if (k == 0) {
      k_gates<<<dim3(2, 32), 256, 0, stream>>>(A0, 2048, Wc, gxf, nullptr,
                                               hbuf, cbuf, Asq, Ah, 0);
    } else {
      k_gates<<<dim3(2, 32), 256, 0, stream>>>(Asq + (size_t)(k - 1) * 2048, 65536, Wg,
                                               gxf, bg, hbuf, cbuf, Asq, Ah, k);
    }
    // htilde = h @ W_attn (hi/lo split, K=3072, f32 out) — round-2-proven numerics
    k_gemm<<<dim3(2, 16), 256, 0, stream>>>(Ah, 3072, W2, 3072, 3072, nullptr,
                                            htl, 1024, nullptr, 0);
    k_attn<<<128, 512, 0, stream>>>(ebf, htl, hbuf, px, W_pt, out, Asq,
                                    out + O4 + (size_t)k * (B_ * S_), k);
  }

  // ---- batched ha for all steps: out[b*32+t] = Asq @ Wo^T + b_out ----
  k_gemm<<<dim3(64, 16), 256, 0, stream>>>(Asq, 2048, Wo, 2048, 2048, b_out,
                                           out + O0, 1024, nullptr, 0);
  k_final<<<512, 256, 0, stream>>>(hbuf, cbuf, out);
}